// Round 7
// baseline (151.130 us; speedup 1.0000x reference)
//
#include <hip/hip_runtime.h>

// PolylineEncoder: h = relu(X@W1+b1); feat = h@W2+b2; masked max over N=64 points.
// B=32 P=512 N=64 C=9 H=128.
// R14 = R12 body (PASSED, VGPR=120, ZERO spill) + LDS-resident weights — the
// single change.  Register-envelope law from R7..R13: this permlane body fits
// ONLY at the 256-reg unified budget (launch_bounds(...,2)); every 64/84-arch
// cap spilled (R10 246B/thr, R11 51B/thr, R13 32B/thr).  R13 proved LDS
// weights help even while spilling (117->92); R14 takes the win without the
// spill.
//   - Block 256 thr / 4 waves, each wave owns 2 polylines end-to-end; grid 2048
//     (= 256 CU x 2 blocks x 4 exact rounds).
//   - LDS: frag-swizzled weights [0,40960) staged once per block via
//     global_load_lds (82MB total, L2-resident); X slots [40960,59392).
//   - ONE __syncthreads; waves fully independent after it.
//   - permlane32/16 in-register h->k transpose (R10-R13 verified), b1 folded
//     into w1sw k=9 row, k9=1.0 in bx, 16-lane shuffle final pool, no Hb.

using bf16x8 = __attribute__((ext_vector_type(8))) short;
using f32x4  = __attribute__((ext_vector_type(4))) float;

#define MFMA32(A,B,C) __builtin_amdgcn_mfma_f32_16x16x32_bf16((A),(B),(C),0,0,0)

__device__ __forceinline__ f32x4 vmax4(f32x4 a, f32x4 b) {
  return __builtin_elementwise_max(a, b);
}

__device__ __forceinline__ unsigned short f2bf(float f) {
  union { float f; unsigned int u; } v; v.f = f;
  unsigned int r = v.u + 0x7fffu + ((v.u >> 16) & 1u);  // RNE
  return (unsigned short)(r >> 16);
}

// hardware packed f32->bf16 (RNE), low=a high=b: 1 VALU per 2 elems
__device__ __forceinline__ unsigned int pk2(float a, float b) {
  unsigned int r;
  asm("v_cvt_pk_bf16_f32 %0, %1, %2" : "=v"(r) : "v"(a), "v"(b));
  return r;
}

__device__ __forceinline__ f32x4 shfl_xor4(f32x4 v, int m) {
  f32x4 r;
  r[0] = __shfl_xor(v[0], m);
  r[1] = __shfl_xor(v[1], m);
  r[2] = __shfl_xor(v[2], m);
  r[3] = __shfl_xor(v[3], m);
  return r;
}

// ---------------- prep1: mask sniff + frag-swizzled weights ----------------
// ws: w1sw @0 (8KB) | w2sw @8192 (32KB) | flag @40960
// w1sw k-row 9 carries b1 (bx supplies k9 = 1.0).
__global__ void prep1(const float* __restrict__ W1, const float* __restrict__ b1,
                      const float* __restrict__ W2, const void* __restrict__ mask,
                      unsigned short* __restrict__ w1sw, unsigned short* __restrict__ w2sw,
                      int* __restrict__ flag) {
  int b = blockIdx.x, t = threadIdx.x;
  if (b == 0) {                      // mask storage sniff over 4096 bytes
    __shared__ int cnt;
    if (t == 0) cnt = 0;
    __syncthreads();
    const unsigned char* mb = (const unsigned char*)mask;
    int local = 0;
    for (int i = t * 16; i < t * 16 + 16; i++) local += (mb[i] != 0) ? 1 : 0;
    atomicAdd(&cnt, local);
    __syncthreads();
    if (t == 0) *flag = (cnt > 2800) ? 1 : 0;   // 1 = byte-wise mask, else int32-wise
  } else if (b <= 2) {
    // w1 A-frags (16x16x32): entry e = th*64 + lane; h=(e>>6)*16+(lane&15)
    int e = (b - 1) * 256 + t;       // 512 entries x 8 halves = 8KB
    int lane = e & 63, grp = e >> 6;
    int li = lane & 15, q = lane >> 4;
    int h = grp * 16 + li;
    int c0 = q * 8;
    #pragma unroll
    for (int j = 0; j < 8; j++) {
      int c = c0 + j;
      float v = (c < 9) ? W1[c * 128 + h] : ((c == 9) ? b1[h] : 0.f);
      w1sw[e * 8 + j] = f2bf(v);
    }
  } else {
    // w2 A-frags (16x16x32): entry e = (wr*16+ks*4+td)*64 + lane; 8 halves each
    int e = (b - 3) * 256 + t;       // 2048 entries x 8 halves = 32KB
    if (e < 2048) {
      int lane = e & 63, grp = e >> 6;
      int wr = grp >> 4, sub = grp & 15;
      int ks = sub >> 2, td = sub & 3;
      int li = lane & 15, q = lane >> 4;
      int d = wr * 64 + td * 16 + li;
      int h0 = ks * 32 + q * 8;
      #pragma unroll
      for (int j = 0; j < 8; j++)
        w2sw[e * 8 + j] = f2bf(W2[(h0 + j) * 128 + d]);
    }
  }
}

// ---------------- main ----------------
// 4 waves/block (256 thr), each wave owns 2 polylines.  Grid 2048.
// LDS: weights [0,40960) | X slots [40960, 59392).
// One __syncthreads (staging done); waves independent afterward.
__global__ __launch_bounds__(256, 2) void poly_main_k(
    const float* __restrict__ X, const void* __restrict__ mask,
    const float* __restrict__ b2g,
    const unsigned short* __restrict__ w1sw, const unsigned short* __restrict__ w2sw,
    const int* __restrict__ flagp, float* __restrict__ out)
{
  __shared__ __align__(16) unsigned char smem[59392];
  const unsigned short* Wl1 = (const unsigned short*)smem;            // 8KB
  const unsigned short* Wl2 = (const unsigned short*)(smem + 8192);   // 32KB

  const int tid  = threadIdx.x;
  const int lane = tid & 63;
  const int w    = tid >> 6;
  const int li   = lane & 15, q = lane >> 4;
  const long long poly0 = (long long)blockIdx.x * 8 + w * 2;

  // ---- stage weights (40960B = 2560 x 16B; 256 thr x 10) into LDS ----
  {
    const char* wg = (const char*)w1sw;   // w1sw,w2sw contiguous in workspace
    #pragma unroll
    for (int k = 0; k < 10; k++)
      __builtin_amdgcn_global_load_lds(
          (const __attribute__((address_space(1))) unsigned int*)(wg + k * 4096 + tid * 16),
          (__attribute__((address_space(3))) unsigned int*)(smem + k * 4096 + w * 1024),
          16, 0, 0);
  }
  // ---- stage this wave's 2 polylines (4608B) into own X slot ----
  {
    const char* xg = (const char*)X + poly0 * 2304;
    char* xl = (char*)smem + 40960 + w * 4608;
    #pragma unroll
    for (int k = 0; k < 4; k++)
      __builtin_amdgcn_global_load_lds(
          (const __attribute__((address_space(1))) unsigned int*)(xg + k * 1024 + lane * 16),
          (__attribute__((address_space(3))) unsigned int*)(xl + k * 1024), 16, 0, 0);
    if (lane < 32)
      __builtin_amdgcn_global_load_lds(
          (const __attribute__((address_space(1))) unsigned int*)(xg + 4096 + lane * 16),
          (__attribute__((address_space(3))) unsigned int*)(xl + 4096), 16, 0, 0);
  }

  const int flag = *flagp;

  __syncthreads();   // weights + X staged (vmcnt drained before barrier)

  #pragma unroll
  for (int pl = 0; pl < 2; pl++) {
    const long long poly = poly0 + pl;
    const float* Xp = (const float*)(smem + 40960 + w * 4608 + pl * 2304);

    // ---- mask: 4 direct loads per lane ----
    float mf[4];
    {
      long long mb = poly * 64 + li;
      if (flag) {
        const unsigned char* mp = (const unsigned char*)mask;
        #pragma unroll
        for (int tm = 0; tm < 4; tm++) mf[tm] = mp[mb + tm * 16] ? 0.f : -4e9f;
      } else {
        const int* mp = (const int*)mask;
        #pragma unroll
        for (int tm = 0; tm < 4; tm++) mf[tm] = mp[mb + tm * 16] ? 0.f : -4e9f;
      }
    }

    f32x4 pooled[8];
    #pragma unroll
    for (int hf = 0; hf < 2; hf++) {
      // ---- layer-1 B-frags for this half's 2 m-tiles (k9 = 1.0 bias row) ----
      bf16x8 bx2[2];
      #pragma unroll
      for (int t = 0; t < 2; t++) {
        const float* xr = Xp + ((hf * 2 + t) * 16 + li) * 9;
        union { bf16x8 v; unsigned int u[4]; } uu;
        uu.u[0] = uu.u[1] = uu.u[2] = uu.u[3] = 0u;
        if (q == 0) {
          uu.u[0] = pk2(xr[0], xr[1]); uu.u[1] = pk2(xr[2], xr[3]);
          uu.u[2] = pk2(xr[4], xr[5]); uu.u[3] = pk2(xr[6], xr[7]);
        } else if (q == 1) {
          uu.u[0] = pk2(xr[8], 1.0f);
        }
        bx2[t] = uu.v;
      }

      // ---- layer 1: all 128 h for these 32 points -> packed bf16 ----
      unsigned int Pp[8][2][2];
      #pragma unroll
      for (int th = 0; th < 8; th++) {
        bf16x8 a1 = *(const bf16x8*)(Wl1 + (th * 64 + lane) * 8);
        f32x4 acc0 = f32x4{0.f, 0.f, 0.f, 0.f};
        f32x4 acc1 = f32x4{0.f, 0.f, 0.f, 0.f};
        acc0 = MFMA32(a1, bx2[0], acc0);
        acc1 = MFMA32(a1, bx2[1], acc1);
        f32x4 v0 = vmax4(acc0, f32x4{0.f, 0.f, 0.f, 0.f});
        f32x4 v1 = vmax4(acc1, f32x4{0.f, 0.f, 0.f, 0.f});
        Pp[th][0][0] = pk2(v0[0], v0[1]); Pp[th][0][1] = pk2(v0[2], v0[3]);
        Pp[th][1][0] = pk2(v1[0], v1[1]); Pp[th][1][1] = pk2(v1[2], v1[3]);
      }

      // ---- in-register h->k transpose (R10-R13 verified) ----
      #pragma unroll
      for (int t = 0; t < 2; t++)
        #pragma unroll
        for (int ks = 0; ks < 4; ks++)
          #pragma unroll
          for (int p = 0; p < 2; p++) {
            asm volatile("v_permlane32_swap_b32 %0, %1"
                         : "+v"(Pp[2 * ks][t][p]), "+v"(Pp[2 * ks + 1][t][p]));
            asm volatile("v_permlane16_swap_b32 %0, %1"
                         : "+v"(Pp[2 * ks][t][p]), "+v"(Pp[2 * ks + 1][t][p]));
          }

      // ---- layer 2, tc-chunked (td pairs), frag reused across both m-tiles ----
      #pragma unroll
      for (int tc = 0; tc < 4; tc++) {
        f32x4 acc[2][2];
        #pragma unroll
        for (int j = 0; j < 2; j++) {
          acc[j][0] = f32x4{0.f, 0.f, 0.f, 0.f};
          acc[j][1] = f32x4{0.f, 0.f, 0.f, 0.f};
        }
        #pragma unroll
        for (int ks = 0; ks < 4; ks++) {
          union { bf16x8 v; unsigned int u[4]; } bh0, bh1;
          bh0.u[0] = Pp[2 * ks][0][0]; bh0.u[1] = Pp[2 * ks][0][1];
          bh0.u[2] = Pp[2 * ks + 1][0][0]; bh0.u[3] = Pp[2 * ks + 1][0][1];
          bh1.u[0] = Pp[2 * ks][1][0]; bh1.u[1] = Pp[2 * ks][1][1];
          bh1.u[2] = Pp[2 * ks + 1][1][0]; bh1.u[3] = Pp[2 * ks + 1][1][1];
          #pragma unroll
          for (int j = 0; j < 2; j++) {
            const int td = tc * 2 + j;
            bf16x8 a2 = *(const bf16x8*)(
                Wl2 + ((((td >> 2) * 16 + ks * 4 + (td & 3)) * 64) + lane) * 8);
            acc[j][0] = MFMA32(a2, bh0.v, acc[j][0]);
            acc[j][1] = MFMA32(a2, bh1.v, acc[j][1]);
          }
        }
        // pool this td-pair over the 2 m-tiles (+ mask), merge across halves
        #pragma unroll
        for (int j = 0; j < 2; j++) {
          const int td = tc * 2 + j;
          f32x4 v = vmax4(acc[j][0] + mf[hf * 2 + 0], acc[j][1] + mf[hf * 2 + 1]);
          pooled[td] = (hf == 0) ? v : vmax4(pooled[td], v);
        }
      }
    }

    // ---- final pool over li: 16-lane shuffle reduce (xor 1,2,4,8) ----
    #pragma unroll
    for (int td = 0; td < 8; td++) {
      #pragma unroll
      for (int sm = 1; sm < 16; sm <<= 1)
        pooled[td] = vmax4(pooled[td], shfl_xor4(pooled[td], sm));
    }

    // li==0 lanes (q=0..3) hold the pool; add b2, zero-fix, 16B stores
    if (li == 0) {
      float* op = out + poly * 128 + q * 4;
      #pragma unroll
      for (int td = 0; td < 8; td++) {
        f32x4 v = pooled[td] + *(const f32x4*)(b2g + td * 16 + q * 4);
        #pragma unroll
        for (int j = 0; j < 4; j++) if (v[j] < -1e8f) v[j] = 0.f;
        *(f32x4*)(op + td * 16) = v;
      }
    }
  }
}

extern "C" void kernel_launch(void* const* d_in, const int* in_sizes, int n_in,
                              void* d_out, int out_size, void* d_ws, size_t ws_size,
                              hipStream_t stream) {
  const float* X    = (const float*)d_in[0];
  const void*  mask = d_in[1];
  const float* W1   = (const float*)d_in[2];
  const float* b1   = (const float*)d_in[3];
  const float* W2   = (const float*)d_in[4];
  const float* b2   = (const float*)d_in[5];
  float* out = (float*)d_out;

  unsigned short* w1sw = (unsigned short*)d_ws;
  unsigned short* w2sw = (unsigned short*)((char*)d_ws + 8192);
  int* flag            = (int*)((char*)d_ws + 40960);

  prep1<<<11, 256, 0, stream>>>(W1, b1, W2, mask, w1sw, w2sw, flag);
  poly_main_k<<<2048, 256, 0, stream>>>(X, mask, b2, w1sw, w2sw, flag, out);
}

// Round 8
// 143.905 us; speedup vs baseline: 1.0502x; 1.0502x over previous
//
#include <hip/hip_runtime.h>

// PolylineEncoder: h = relu(X@W1+b1); feat = h@W2+b2; masked max over N=64 points.
// B=32 P=512 N=64 C=9 H=128.
// R15 = R14 (PASSED, zero spill, LDS weights, 80.7us) minus its LDS-pipe wall.
//   R14 accounting: ~160 ds_read_b128 + 256 ds_bpermute per wave ~ 4.1K cyc on
//   the per-CU LDS pipe -> 131K cyc/CU ~ 55us of DS issue = the bottleneck.
//   Changes (DS ops cut ~3x):
//   1. Final 16-lane max-reduce via DPP butterfly (quad_perm xor1/xor2 +
//      row_half_mirror + row_mirror) -> pure VALU, kills all 256 bpermutes.
//   2. Full-polyline layer1/layer2 (no halves): each frag ds_read feeds 4
//      MFMAs instead of 2 (layer2 reads 128->64, layer1 32->16 per wave).
//      bhv[4][4] B-operand tuples built once per polyline after transpose.
//   Register audit ~155 < 256 unified @ launch_bounds(256,2) (R12 envelope law;
//   sentinel = WRITE_SIZE, must stay ~8.2MB).
//   Unchanged: prep1, frag layouts, permlane h->k transpose, b1-in-w1sw k=9,
//   LDS weight staging, per-wave X slots, mask path, li==0 coalesced stores.

using bf16x8 = __attribute__((ext_vector_type(8))) short;
using f32x4  = __attribute__((ext_vector_type(4))) float;

#define MFMA32(A,B,C) __builtin_amdgcn_mfma_f32_16x16x32_bf16((A),(B),(C),0,0,0)

__device__ __forceinline__ f32x4 vmax4(f32x4 a, f32x4 b) {
  return __builtin_elementwise_max(a, b);
}

__device__ __forceinline__ unsigned short f2bf(float f) {
  union { float f; unsigned int u; } v; v.f = f;
  unsigned int r = v.u + 0x7fffu + ((v.u >> 16) & 1u);  // RNE
  return (unsigned short)(r >> 16);
}

// hardware packed f32->bf16 (RNE), low=a high=b: 1 VALU per 2 elems
__device__ __forceinline__ unsigned int pk2(float a, float b) {
  unsigned int r;
  asm("v_cvt_pk_bf16_f32 %0, %1, %2" : "=v"(r) : "v"(a), "v"(b));
  return r;
}

// DPP lane-permute + max, row scope (16 lanes).  CTRL: 0xB1 = quad_perm(1,0,3,2)
// [xor1], 0x4E = quad_perm(2,3,0,1) [xor2], 0x141 = row_half_mirror [8-group],
// 0x140 = row_mirror [16-group].  Butterfly of the 4 = full 16-lane max.
template <int CTRL>
__device__ __forceinline__ float dppmaxf(float x) {
  union { float f; int i; } s, p;
  s.f = x;
  p.i = __builtin_amdgcn_update_dpp(s.i, s.i, CTRL, 0xF, 0xF, true);
  return fmaxf(x, p.f);
}
template <int CTRL>
__device__ __forceinline__ f32x4 dppmax4(f32x4 v) {
  f32x4 r;
  r[0] = dppmaxf<CTRL>(v[0]); r[1] = dppmaxf<CTRL>(v[1]);
  r[2] = dppmaxf<CTRL>(v[2]); r[3] = dppmaxf<CTRL>(v[3]);
  return r;
}

// ---------------- prep1: mask sniff + frag-swizzled weights ----------------
// ws: w1sw @0 (8KB) | w2sw @8192 (32KB) | flag @40960
// w1sw k-row 9 carries b1 (bx supplies k9 = 1.0).
__global__ void prep1(const float* __restrict__ W1, const float* __restrict__ b1,
                      const float* __restrict__ W2, const void* __restrict__ mask,
                      unsigned short* __restrict__ w1sw, unsigned short* __restrict__ w2sw,
                      int* __restrict__ flag) {
  int b = blockIdx.x, t = threadIdx.x;
  if (b == 0) {                      // mask storage sniff over 4096 bytes
    __shared__ int cnt;
    if (t == 0) cnt = 0;
    __syncthreads();
    const unsigned char* mb = (const unsigned char*)mask;
    int local = 0;
    for (int i = t * 16; i < t * 16 + 16; i++) local += (mb[i] != 0) ? 1 : 0;
    atomicAdd(&cnt, local);
    __syncthreads();
    if (t == 0) *flag = (cnt > 2800) ? 1 : 0;   // 1 = byte-wise mask, else int32-wise
  } else if (b <= 2) {
    // w1 A-frags (16x16x32): entry e = th*64 + lane; h=(e>>6)*16+(lane&15)
    int e = (b - 1) * 256 + t;       // 512 entries x 8 halves = 8KB
    int lane = e & 63, grp = e >> 6;
    int li = lane & 15, q = lane >> 4;
    int h = grp * 16 + li;
    int c0 = q * 8;
    #pragma unroll
    for (int j = 0; j < 8; j++) {
      int c = c0 + j;
      float v = (c < 9) ? W1[c * 128 + h] : ((c == 9) ? b1[h] : 0.f);
      w1sw[e * 8 + j] = f2bf(v);
    }
  } else {
    // w2 A-frags (16x16x32): entry e = (wr*16+ks*4+td)*64 + lane; 8 halves each
    int e = (b - 3) * 256 + t;       // 2048 entries x 8 halves = 32KB
    if (e < 2048) {
      int lane = e & 63, grp = e >> 6;
      int wr = grp >> 4, sub = grp & 15;
      int ks = sub >> 2, td = sub & 3;
      int li = lane & 15, q = lane >> 4;
      int d = wr * 64 + td * 16 + li;
      int h0 = ks * 32 + q * 8;
      #pragma unroll
      for (int j = 0; j < 8; j++)
        w2sw[e * 8 + j] = f2bf(W2[(h0 + j) * 128 + d]);
    }
  }
}

// ---------------- main ----------------
// 4 waves/block (256 thr), each wave owns 2 polylines.  Grid 2048.
// LDS: weights [0,40960) | X slots [40960, 59392).
// One __syncthreads (staging done); waves independent afterward.
__global__ __launch_bounds__(256, 2) void poly_main_k(
    const float* __restrict__ X, const void* __restrict__ mask,
    const float* __restrict__ b2g,
    const unsigned short* __restrict__ w1sw, const unsigned short* __restrict__ w2sw,
    const int* __restrict__ flagp, float* __restrict__ out)
{
  __shared__ __align__(16) unsigned char smem[59392];
  const unsigned short* Wl1 = (const unsigned short*)smem;            // 8KB
  const unsigned short* Wl2 = (const unsigned short*)(smem + 8192);   // 32KB

  const int tid  = threadIdx.x;
  const int lane = tid & 63;
  const int w    = tid >> 6;
  const int li   = lane & 15, q = lane >> 4;
  const long long poly0 = (long long)blockIdx.x * 8 + w * 2;

  // ---- stage weights (40960B = 2560 x 16B; 256 thr x 10) into LDS ----
  {
    const char* wg = (const char*)w1sw;   // w1sw,w2sw contiguous in workspace
    #pragma unroll
    for (int k = 0; k < 10; k++)
      __builtin_amdgcn_global_load_lds(
          (const __attribute__((address_space(1))) unsigned int*)(wg + k * 4096 + tid * 16),
          (__attribute__((address_space(3))) unsigned int*)(smem + k * 4096 + w * 1024),
          16, 0, 0);
  }
  // ---- stage this wave's 2 polylines (4608B) into own X slot ----
  {
    const char* xg = (const char*)X + poly0 * 2304;
    char* xl = (char*)smem + 40960 + w * 4608;
    #pragma unroll
    for (int k = 0; k < 4; k++)
      __builtin_amdgcn_global_load_lds(
          (const __attribute__((address_space(1))) unsigned int*)(xg + k * 1024 + lane * 16),
          (__attribute__((address_space(3))) unsigned int*)(xl + k * 1024), 16, 0, 0);
    if (lane < 32)
      __builtin_amdgcn_global_load_lds(
          (const __attribute__((address_space(1))) unsigned int*)(xg + 4096 + lane * 16),
          (__attribute__((address_space(3))) unsigned int*)(xl + 4096), 16, 0, 0);
  }

  const int flag = *flagp;

  __syncthreads();   // weights + X staged (vmcnt drained before barrier)

  #pragma unroll
  for (int pl = 0; pl < 2; pl++) {
    const long long poly = poly0 + pl;
    const float* Xp = (const float*)(smem + 40960 + w * 4608 + pl * 2304);

    // ---- mask: 4 direct loads per lane ----
    float mf[4];
    {
      long long mb = poly * 64 + li;
      if (flag) {
        const unsigned char* mp = (const unsigned char*)mask;
        #pragma unroll
        for (int tm = 0; tm < 4; tm++) mf[tm] = mp[mb + tm * 16] ? 0.f : -4e9f;
      } else {
        const int* mp = (const int*)mask;
        #pragma unroll
        for (int tm = 0; tm < 4; tm++) mf[tm] = mp[mb + tm * 16] ? 0.f : -4e9f;
      }
    }

    // ---- layer-1 B-frags for all 4 m-tiles (k9 = 1.0 bias row) ----
    bf16x8 bx[4];
    #pragma unroll
    for (int mt = 0; mt < 4; mt++) {
      const float* xr = Xp + (mt * 16 + li) * 9;
      union { bf16x8 v; unsigned int u[4]; } uu;
      uu.u[0] = uu.u[1] = uu.u[2] = uu.u[3] = 0u;
      if (q == 0) {
        uu.u[0] = pk2(xr[0], xr[1]); uu.u[1] = pk2(xr[2], xr[3]);
        uu.u[2] = pk2(xr[4], xr[5]); uu.u[3] = pk2(xr[6], xr[7]);
      } else if (q == 1) {
        uu.u[0] = pk2(xr[8], 1.0f);
      }
      bx[mt] = uu.v;
    }

    // ---- layer 1: all 128 h for all 64 points; each frag read -> 4 MFMAs ----
    unsigned int Pp[8][4][2];
    #pragma unroll
    for (int th = 0; th < 8; th++) {
      bf16x8 a1 = *(const bf16x8*)(Wl1 + (th * 64 + lane) * 8);
      f32x4 acc[4];
      #pragma unroll
      for (int mt = 0; mt < 4; mt++) acc[mt] = f32x4{0.f, 0.f, 0.f, 0.f};
      #pragma unroll
      for (int mt = 0; mt < 4; mt++) acc[mt] = MFMA32(a1, bx[mt], acc[mt]);
      #pragma unroll
      for (int mt = 0; mt < 4; mt++) {
        f32x4 v = vmax4(acc[mt], f32x4{0.f, 0.f, 0.f, 0.f});
        Pp[th][mt][0] = pk2(v[0], v[1]);
        Pp[th][mt][1] = pk2(v[2], v[3]);
      }
    }

    // ---- in-register h->k transpose (R10-R14 verified) ----
    #pragma unroll
    for (int mt = 0; mt < 4; mt++)
      #pragma unroll
      for (int ks = 0; ks < 4; ks++)
        #pragma unroll
        for (int p = 0; p < 2; p++) {
          asm volatile("v_permlane32_swap_b32 %0, %1"
                       : "+v"(Pp[2 * ks][mt][p]), "+v"(Pp[2 * ks + 1][mt][p]));
          asm volatile("v_permlane16_swap_b32 %0, %1"
                       : "+v"(Pp[2 * ks][mt][p]), "+v"(Pp[2 * ks + 1][mt][p]));
        }

    // ---- build B-operand tuples once ----
    bf16x8 bhv[4][4];   // [ks][mt]
    #pragma unroll
    for (int ks = 0; ks < 4; ks++)
      #pragma unroll
      for (int mt = 0; mt < 4; mt++) {
        union { bf16x8 v; unsigned int u[4]; } bh;
        bh.u[0] = Pp[2 * ks][mt][0];
        bh.u[1] = Pp[2 * ks][mt][1];
        bh.u[2] = Pp[2 * ks + 1][mt][0];
        bh.u[3] = Pp[2 * ks + 1][mt][1];
        bhv[ks][mt] = bh.v;
      }

    // ---- layer 2: each a2 frag read feeds 4 m-tile MFMAs ----
    f32x4 pooled[8];
    #pragma unroll
    for (int tc = 0; tc < 4; tc++) {
      f32x4 acc2[2][4];
      #pragma unroll
      for (int j = 0; j < 2; j++)
        #pragma unroll
        for (int mt = 0; mt < 4; mt++) acc2[j][mt] = f32x4{0.f, 0.f, 0.f, 0.f};
      #pragma unroll
      for (int ks = 0; ks < 4; ks++) {
        #pragma unroll
        for (int j = 0; j < 2; j++) {
          const int td = tc * 2 + j;
          bf16x8 a2 = *(const bf16x8*)(
              Wl2 + ((((td >> 2) * 16 + ks * 4 + (td & 3)) * 64) + lane) * 8);
          #pragma unroll
          for (int mt = 0; mt < 4; mt++)
            acc2[j][mt] = MFMA32(a2, bhv[ks][mt], acc2[j][mt]);
        }
      }
      // pool over the 4 m-tiles (+ mask offsets)
      #pragma unroll
      for (int j = 0; j < 2; j++) {
        const int td = tc * 2 + j;
        f32x4 v = acc2[j][0] + mf[0];
        #pragma unroll
        for (int mt = 1; mt < 4; mt++) v = vmax4(v, acc2[j][mt] + mf[mt]);
        pooled[td] = v;
      }
    }

    // ---- final pool over li: DPP butterfly (row scope), zero DS ops ----
    #pragma unroll
    for (int td = 0; td < 8; td++) {
      pooled[td] = dppmax4<0xB1>(pooled[td]);   // xor1 (quad_perm 1,0,3,2)
      pooled[td] = dppmax4<0x4E>(pooled[td]);   // xor2 (quad_perm 2,3,0,1)
      pooled[td] = dppmax4<0x141>(pooled[td]);  // row_half_mirror (8-group)
      pooled[td] = dppmax4<0x140>(pooled[td]);  // row_mirror (16-group)
    }

    // li==0 lanes (q=0..3) hold the pool; add b2, zero-fix, 16B stores
    if (li == 0) {
      float* op = out + poly * 128 + q * 4;
      #pragma unroll
      for (int td = 0; td < 8; td++) {
        f32x4 v = pooled[td] + *(const f32x4*)(b2g + td * 16 + q * 4);
        #pragma unroll
        for (int j = 0; j < 4; j++) if (v[j] < -1e8f) v[j] = 0.f;
        *(f32x4*)(op + td * 16) = v;
      }
    }
  }
}

extern "C" void kernel_launch(void* const* d_in, const int* in_sizes, int n_in,
                              void* d_out, int out_size, void* d_ws, size_t ws_size,
                              hipStream_t stream) {
  const float* X    = (const float*)d_in[0];
  const void*  mask = d_in[1];
  const float* W1   = (const float*)d_in[2];
  const float* b1   = (const float*)d_in[3];
  const float* W2   = (const float*)d_in[4];
  const float* b2   = (const float*)d_in[5];
  float* out = (float*)d_out;

  unsigned short* w1sw = (unsigned short*)d_ws;
  unsigned short* w2sw = (unsigned short*)((char*)d_ws + 8192);
  int* flag            = (int*)((char*)d_ws + 40960);

  prep1<<<11, 256, 0, stream>>>(W1, b1, W2, mask, w1sw, w2sw, flag);
  poly_main_k<<<2048, 256, 0, stream>>>(X, mask, b2, w1sw, w2sw, flag, out);
}